// Round 6
// baseline (1268.937 us; speedup 1.0000x reference)
//
#include <hip/hip_runtime.h>

// ChildSumTreeLSTM on a static 4-ary heap tree.
// N=8192, H=256, D=300, K=4, OUT=4. Leaves = 2048..8191. Internal 0..2047, 7 levels.
// Structure: gx_gemm (parallel, big) + ONE persistent cooperative kernel for the
// whole tree recurrence with a lean hand-rolled device barrier (the ~20 us/launch
// kernel-boundary cost was the measured bottleneck; ROCm grid.sync costs ~57 us).
// F-restructure: F[n] = Wf·h_n computed densely per contiguous level range, so the
// serial chain is iou-GEMM(hs) + F-GEMM(prev level) per level.
// Workspace (50.3 MB + 8 B):
//   gx : [8192][1024] f32   (gate order i,f,o,u)
//   Hb : [8192][256]  f32
//   Cb : [8192][256]  f32
//   F  ([8192][256]) aliases gx rows 2048..4095 (leaf rows, dead after leaf phase)
//   D  (3*1024*256)  aliases gx rows 4096..4863
//   bar: 2 x u32 after Cb

#define N_NODES 8192
#define HDIM 256
#define DDIM 300
#define GXC 1024
#define LEAF_FIRST 2048
#define WH_STRIDE 65536   // 256*256
#define NBLK 256

__device__ __forceinline__ float sigf(float x) { return 1.0f / (1.0f + __expf(-x)); }

// Lean device barrier: generation-based, agent scope. All NBLK blocks participate.
__device__ __forceinline__ void gbar(unsigned* bar, int nblk) {
    __syncthreads();
    if (threadIdx.x == 0) {
        __threadfence();
        const unsigned g = __hip_atomic_load(bar + 1, __ATOMIC_RELAXED,
                                             __HIP_MEMORY_SCOPE_AGENT);
        const unsigned old = __hip_atomic_fetch_add(bar, 1u, __ATOMIC_RELEASE,
                                                    __HIP_MEMORY_SCOPE_AGENT);
        if (old == (unsigned)(nblk - 1)) {
            __hip_atomic_store(bar, 0u, __ATOMIC_RELAXED, __HIP_MEMORY_SCOPE_AGENT);
            __hip_atomic_fetch_add(bar + 1, 1u, __ATOMIC_RELEASE,
                                   __HIP_MEMORY_SCOPE_AGENT);
        } else {
            while (__hip_atomic_load(bar + 1, __ATOMIC_ACQUIRE,
                                     __HIP_MEMORY_SCOPE_AGENT) == g)
                __builtin_amdgcn_s_sleep(8);
            __threadfence();
        }
    }
    __syncthreads();
}

// ---------- Kernel 1: gx[n][c] = emb[xs[n]] · Wx[c] + bx[c]  (64x64 tile) ----
__global__ __launch_bounds__(256) void gx_gemm(
    const int* __restrict__ xs, const float* __restrict__ emb,
    const float* __restrict__ Wx, const float* __restrict__ bx,
    float* __restrict__ gx)
{
    __shared__ __align__(16) float As[16][68];
    __shared__ __align__(16) float Bs[16][68];
    const int tid  = threadIdx.x;
    const int n0   = blockIdx.y * 64;
    const int c0   = blockIdx.x * 64;
    const int sr   = tid >> 2;
    const int sk   = (tid & 3) << 2;
    const int trow = (tid >> 4) << 2;
    const int tcol = (tid & 15) << 2;

    const long arow = (long)xs[n0 + sr] * DDIM;
    const long brow = (long)(c0 + sr) * DDIM;

    float acc[4][4] = {};

    for (int k0 = 0; k0 < DDIM; k0 += 16) {
        float4 av = make_float4(0.f, 0.f, 0.f, 0.f), bv = av;
        if (k0 + sk < DDIM) {
            av = *(const float4*)(emb + arow + k0 + sk);
            bv = *(const float4*)(Wx  + brow + k0 + sk);
        }
        __syncthreads();
        As[sk+0][sr] = av.x; As[sk+1][sr] = av.y; As[sk+2][sr] = av.z; As[sk+3][sr] = av.w;
        Bs[sk+0][sr] = bv.x; Bs[sk+1][sr] = bv.y; Bs[sk+2][sr] = bv.z; Bs[sk+3][sr] = bv.w;
        __syncthreads();
        #pragma unroll
        for (int k = 0; k < 16; k++) {
            const float4 a = *(const float4*)&As[k][trow];
            const float4 b = *(const float4*)&Bs[k][tcol];
            const float avv[4] = {a.x, a.y, a.z, a.w};
            const float bvv[4] = {b.x, b.y, b.z, b.w};
            #pragma unroll
            for (int i = 0; i < 4; i++)
                #pragma unroll
                for (int j = 0; j < 4; j++)
                    acc[i][j] = fmaf(avv[i], bvv[j], acc[i][j]);
        }
    }

    #pragma unroll
    for (int i = 0; i < 4; i++) {
        const int col = c0 + tcol;
        float4 r;
        r.x = acc[i][0] + bx[col + 0];
        r.y = acc[i][1] + bx[col + 1];
        r.z = acc[i][2] + bx[col + 2];
        r.w = acc[i][3] + bx[col + 3];
        *(float4*)(gx + (long)(n0 + trow + i) * GXC + col) = r;
    }
}

// ---------- Kernel 2: persistent tree kernel --------------------------------
__global__ __launch_bounds__(256) void tree_mega(
    const float* __restrict__ gx, const int* __restrict__ child_idx,
    const float* __restrict__ child_mask, const float* __restrict__ Wh,
    const float* __restrict__ bh, const float* __restrict__ Wout,
    const float* __restrict__ bout, float* __restrict__ Hb,
    float* __restrict__ Cb, float* __restrict__ F, float* __restrict__ D,
    float* __restrict__ out, unsigned* bar)
{
    const int bid = blockIdx.x;
    const int nB  = gridDim.x;
    const int tid = threadIdx.x;

    __shared__ __align__(16) float Xs[16][68];
    __shared__ __align__(16) float Ws[16][68];

    const int sr   = tid >> 2;
    const int sk   = (tid & 3) << 2;
    const int trow = (tid >> 4) << 2;
    const int tcol = (tid & 15) << 2;
    const float* Wf = Wh + 1 * WH_STRIDE;

    // ---- Phase 0: leaves (elementwise) ----
    for (int node = LEAF_FIRST + bid; node < N_NODES; node += nB) {
        const float* g = gx + (long)node * GXC;
        const float gi = g[tid]       + bh[tid];
        const float go = g[512 + tid] + bh[512 + tid];
        const float gu = g[768 + tid] + bh[768 + tid];
        const float c  = sigf(gi) * tanhf(gu);
        const float h  = sigf(go) * tanhf(c);
        Hb[(long)node * HDIM + tid] = h;
        Cb[(long)node * HDIM + tid] = c;
    }
    gbar(bar, nB);

    // ---- Phase LF: F[n] = Wf·h_n for all 6144 leaves (64x64 tiles) ----
    {
        const int cols = N_NODES - LEAF_FIRST;   // 6144
        const int ct   = cols / 64;              // 96
        for (int tile = bid; tile < ct * 4; tile += nB) {
            const int c0 = (tile % ct) * 64;
            const int r0 = (tile / ct) * 64;
            const long frow = (long)(LEAF_FIRST + c0 + sr) * HDIM;
            const long wrow = (long)(r0 + sr) * HDIM;
            float acc[4][4] = {};
            for (int k0 = 0; k0 < HDIM; k0 += 16) {
                const float4 xv = *(const float4*)(Hb + frow + k0 + sk);
                const float4 wv = *(const float4*)(Wf + wrow + k0 + sk);
                __syncthreads();
                Xs[sk+0][sr] = xv.x; Xs[sk+1][sr] = xv.y; Xs[sk+2][sr] = xv.z; Xs[sk+3][sr] = xv.w;
                Ws[sk+0][sr] = wv.x; Ws[sk+1][sr] = wv.y; Ws[sk+2][sr] = wv.z; Ws[sk+3][sr] = wv.w;
                __syncthreads();
                #pragma unroll
                for (int k = 0; k < 16; k++) {
                    const float4 a = *(const float4*)&Ws[k][trow];
                    const float4 b = *(const float4*)&Xs[k][tcol];
                    const float avv[4] = {a.x, a.y, a.z, a.w};
                    const float bvv[4] = {b.x, b.y, b.z, b.w};
                    #pragma unroll
                    for (int i = 0; i < 4; i++)
                        #pragma unroll
                        for (int j = 0; j < 4; j++)
                            acc[i][j] = fmaf(avv[i], bvv[j], acc[i][j]);
                }
            }
            #pragma unroll
            for (int j = 0; j < 4; j++) {
                float4 r;
                r.x = acc[0][j]; r.y = acc[1][j]; r.z = acc[2][j]; r.w = acc[3][j];
                *(float4*)(F + (long)(LEAF_FIRST + c0 + tcol + j) * HDIM + r0 + trow) = r;
            }
        }
    }
    gbar(bar, nB);

    const int pf[7] = {1365, 341, 85, 21, 5, 1, 0};
    const int pc[7] = { 683, 1024, 256, 64, 16, 4, 1};

    for (int p = 0; p < 7; p++) {
        const int first  = pf[p];
        const int M      = pc[p];
        const int firstF = (p > 0) ? pf[p - 1] : 0;
        const int MF     = (p > 0) ? pc[p - 1] : 0;
        const int ctM    = (M + 63) / 64;
        const int ctF    = (MF + 63) / 64;
        const int niou   = ctM * 12;             // 3 sections x 4 row-tiles
        const int ntot   = niou + ctF * 4;

        // ---- Phase A: iou-GEMM on hs(level p) + F-GEMM on h(level p-1) ----
        for (int tile = bid; tile < ntot; tile += nB) {
            int c0, r0, sec;
            bool isF;
            if (tile < niou) {
                isF = false;
                c0  = (tile % ctM) * 64;
                const int rest = tile / ctM;
                sec = rest % 3;                  // 0=i 1=o 2=u
                r0  = (rest / 3) * 64;
            } else {
                isF = true;
                const int ft = tile - niou;
                c0  = (ft % ctF) * 64;
                r0  = (ft / ctF) * 64;
                sec = 3;
            }
            const int cols = isF ? MF : M;
            const int nl   = c0 + sr;
            const bool valid = nl < cols;

            const float* Wg;
            if      (sec == 0) Wg = Wh;                  // i
            else if (sec == 1) Wg = Wh + 2 * WH_STRIDE;  // o
            else if (sec == 2) Wg = Wh + 3 * WH_STRIDE;  // u
            else               Wg = Wf;                  // f

            int   ci[4];
            float cm[4] = {0.f, 0.f, 0.f, 0.f};
            if (!isF && valid) {
                const int n = first + nl;
                #pragma unroll
                for (int k = 0; k < 4; k++) {
                    ci[k] = child_idx[n * 4 + k];
                    cm[k] = child_mask[n * 4 + k];
                }
            }
            const long wrow = (long)(r0 + sr) * HDIM;
            const long frow = (long)(firstF + nl) * HDIM;

            float acc[4][4] = {};
            for (int k0 = 0; k0 < HDIM; k0 += 16) {
                float4 xv = make_float4(0.f, 0.f, 0.f, 0.f);
                if (valid) {
                    if (!isF) {
                        #pragma unroll
                        for (int k = 0; k < 4; k++)
                            if (cm[k] != 0.f) {
                                const float4 hv = *(const float4*)(Hb + (long)ci[k] * HDIM + k0 + sk);
                                xv.x += hv.x; xv.y += hv.y; xv.z += hv.z; xv.w += hv.w;
                            }
                    } else {
                        xv = *(const float4*)(Hb + frow + k0 + sk);
                    }
                }
                const float4 wv = *(const float4*)(Wg + wrow + k0 + sk);
                __syncthreads();
                Xs[sk+0][sr] = xv.x; Xs[sk+1][sr] = xv.y; Xs[sk+2][sr] = xv.z; Xs[sk+3][sr] = xv.w;
                Ws[sk+0][sr] = wv.x; Ws[sk+1][sr] = wv.y; Ws[sk+2][sr] = wv.z; Ws[sk+3][sr] = wv.w;
                __syncthreads();
                #pragma unroll
                for (int k = 0; k < 16; k++) {
                    const float4 a = *(const float4*)&Ws[k][trow];
                    const float4 b = *(const float4*)&Xs[k][tcol];
                    const float avv[4] = {a.x, a.y, a.z, a.w};
                    const float bvv[4] = {b.x, b.y, b.z, b.w};
                    #pragma unroll
                    for (int i = 0; i < 4; i++)
                        #pragma unroll
                        for (int j = 0; j < 4; j++)
                            acc[i][j] = fmaf(avv[i], bvv[j], acc[i][j]);
                }
            }
            #pragma unroll
            for (int j = 0; j < 4; j++) {
                const int col = c0 + tcol + j;
                if (col < cols) {
                    float4 r;
                    r.x = acc[0][j]; r.y = acc[1][j]; r.z = acc[2][j]; r.w = acc[3][j];
                    if (!isF)
                        *(float4*)(D + ((long)(sec * M + col)) * HDIM + r0 + trow) = r;
                    else
                        *(float4*)(F + ((long)(firstF + col)) * HDIM + r0 + trow) = r;
                }
            }
        }
        gbar(bar, nB);

        // ---- Phase B: pointwise combine ----
        for (int nl = bid; nl < M; nl += nB) {
            const int n = first + nl;
            const float di = D[((long)(0 * M + nl)) * HDIM + tid];
            const float dO = D[((long)(1 * M + nl)) * HDIM + tid];
            const float du = D[((long)(2 * M + nl)) * HDIM + tid];
            const float* g = gx + (long)n * GXC;
            const float gi  = g[tid]       + bh[tid]       + di;
            const float gfb = g[256 + tid] + bh[256 + tid];
            const float go  = g[512 + tid] + bh[512 + tid] + dO;
            const float gu  = g[768 + tid] + bh[768 + tid] + du;

            float c = sigf(gi) * tanhf(gu);
            #pragma unroll
            for (int k = 0; k < 4; k++) {
                const float m = child_mask[n * 4 + k];
                if (m != 0.f) {
                    const int cidx = child_idx[n * 4 + k];
                    const float df = F[(long)cidx * HDIM + tid];
                    const float cc = Cb[(long)cidx * HDIM + tid];
                    c = fmaf(sigf(gfb + df), cc, c);
                }
            }
            const float h = sigf(go) * tanhf(c);
            Hb[(long)n * HDIM + tid] = h;
            Cb[(long)n * HDIM + tid] = c;
        }
        gbar(bar, nB);
    }

    // ---- Output phase: block 0 ----
    if (bid == 0) {
        const int o    = tid >> 6;
        const int lane = tid & 63;
        float s = 0.f;
        for (int j = lane; j < HDIM; j += 64)
            s = fmaf(Wout[o * HDIM + j], Hb[j], s);
        #pragma unroll
        for (int off = 32; off > 0; off >>= 1)
            s += __shfl_down(s, off, 64);
        __shared__ float logits[4];
        if (lane == 0) logits[o] = s + bout[o];
        __syncthreads();
        if (tid == 0) {
            float m = logits[0];
            #pragma unroll
            for (int i = 1; i < 4; i++) m = fmaxf(m, logits[i]);
            float se = 0.f;
            #pragma unroll
            for (int i = 0; i < 4; i++) se += __expf(logits[i] - m);
            const float lse = m + __logf(se);
            #pragma unroll
            for (int i = 0; i < 4; i++) out[i] = logits[i] - lse;
        }
    }
}

extern "C" void kernel_launch(void* const* d_in, const int* in_sizes, int n_in,
                              void* d_out, int out_size, void* d_ws, size_t ws_size,
                              hipStream_t stream)
{
    const int*   xs         = (const int*)  d_in[0];
    const int*   child_idx  = (const int*)  d_in[1];
    const float* child_mask = (const float*)d_in[2];
    const float* emb        = (const float*)d_in[3];
    const float* Wx         = (const float*)d_in[4];
    const float* bx         = (const float*)d_in[5];
    const float* Wh         = (const float*)d_in[6];
    const float* bh         = (const float*)d_in[7];
    const float* Wout       = (const float*)d_in[8];
    const float* bout       = (const float*)d_in[9];
    float* out = (float*)d_out;

    float* gxb  = (float*)d_ws;                           // [8192][1024]
    float* Hb   = gxb + (size_t)N_NODES * GXC;            // [8192][256]
    float* Cb   = Hb  + (size_t)N_NODES * HDIM;           // [8192][256]
    float* Fbuf = gxb + (size_t)LEAF_FIRST * GXC;         // aliases gx rows 2048..4095
    float* Dbuf = gxb + (size_t)4096 * GXC;               // aliases gx rows 4096..4863
    unsigned* bar = (unsigned*)(Cb + (size_t)N_NODES * HDIM);

    hipMemsetAsync(bar, 0, 2 * sizeof(unsigned), stream);
    gx_gemm<<<dim3(GXC / 64, N_NODES / 64), 256, 0, stream>>>(xs, emb, Wx, bx, gxb);

    void* args[] = {(void*)&gxb, (void*)&child_idx, (void*)&child_mask,
                    (void*)&Wh, (void*)&bh, (void*)&Wout, (void*)&bout,
                    (void*)&Hb, (void*)&Cb, (void*)&Fbuf, (void*)&Dbuf,
                    (void*)&out, (void*)&bar};
    hipLaunchCooperativeKernel((void*)tree_mega, dim3(NBLK), dim3(256),
                               args, 0, stream);
}

// Round 7
// 983.716 us; speedup vs baseline: 1.2899x; 1.2899x over previous
//
#include <hip/hip_runtime.h>

// ChildSumTreeLSTM on a static 4-ary heap tree.
// N=8192, H=256, D=300, K=4, OUT=4. Leaves = 2048..8191. Internal 0..2047, 7 levels.
// Structure (measured-driven): multi-kernel stream launches ONLY — in-kernel
// device-wide sync costs ~60-70 us/barrier on gfx950 (rounds 4+6), launch
// boundary ~10-20 us. Levels with M<=256 use a fused one-block-per-node kernel
// (GEMV by shuffle-reduce + pointwise, no D round-trip); big levels (683,1024)
// use tiled 64x64 GEMM with register double-buffering + separate pointwise.
// Workspace (50.3 MB):
//   gx : [8192][1024] f32   (gate order i,f,o,u)
//   Hb : [8192][256]  f32
//   Cb : [8192][256]  f32
//   D  (7*1024*256 = 7.3 MB) aliases gx leaf rows (dead after leaf_kernel).

#define N_NODES 8192
#define HDIM 256
#define DDIM 300
#define GXC 1024
#define LEAF_FIRST 2048
#define WH_STRIDE 65536   // 256*256

__device__ __forceinline__ float sigf(float x) { return 1.0f / (1.0f + __expf(-x)); }

__device__ __forceinline__ float dot4(float acc, float4 a, float4 b) {
    acc = fmaf(a.x, b.x, acc);
    acc = fmaf(a.y, b.y, acc);
    acc = fmaf(a.z, b.z, acc);
    acc = fmaf(a.w, b.w, acc);
    return acc;
}

// ---------- Kernel 1: gx[n][c] = emb[xs[n]] · Wx[c] + bx[c]  (64x64 tile) ----
// Leaf rows (n>=2048) never use f-gate cols [256,512) -> skip those blocks.
__global__ __launch_bounds__(256) void gx_gemm(
    const int* __restrict__ xs, const float* __restrict__ emb,
    const float* __restrict__ Wx, const float* __restrict__ bx,
    float* __restrict__ gx)
{
    const int n0 = blockIdx.y * 64;
    const int c0 = blockIdx.x * 64;
    if (n0 >= LEAF_FIRST && c0 >= 256 && c0 < 512) return;  // dead leaf f-cols

    __shared__ __align__(16) float As[16][68];
    __shared__ __align__(16) float Bs[16][68];
    const int tid  = threadIdx.x;
    const int sr   = tid >> 2;
    const int sk   = (tid & 3) << 2;
    const int trow = (tid >> 4) << 2;
    const int tcol = (tid & 15) << 2;

    const long arow = (long)xs[n0 + sr] * DDIM;
    const long brow = (long)(c0 + sr) * DDIM;

    float acc[4][4] = {};

    float4 av = make_float4(0.f, 0.f, 0.f, 0.f), bv = av;
    if (sk < DDIM) {
        av = *(const float4*)(emb + arow + sk);
        bv = *(const float4*)(Wx  + brow + sk);
    }
    for (int k0 = 0; k0 < DDIM; k0 += 16) {
        __syncthreads();
        As[sk+0][sr] = av.x; As[sk+1][sr] = av.y; As[sk+2][sr] = av.z; As[sk+3][sr] = av.w;
        Bs[sk+0][sr] = bv.x; Bs[sk+1][sr] = bv.y; Bs[sk+2][sr] = bv.z; Bs[sk+3][sr] = bv.w;
        __syncthreads();
        // Prefetch next chunk BEFORE the FMA block (overlap load with compute).
        const int kn = k0 + 16;
        float4 av2 = make_float4(0.f, 0.f, 0.f, 0.f), bv2 = av2;
        if (kn < DDIM && kn + sk < DDIM) {
            av2 = *(const float4*)(emb + arow + kn + sk);
            bv2 = *(const float4*)(Wx  + brow + kn + sk);
        }
        #pragma unroll
        for (int k = 0; k < 16; k++) {
            const float4 a = *(const float4*)&As[k][trow];
            const float4 b = *(const float4*)&Bs[k][tcol];
            const float avv[4] = {a.x, a.y, a.z, a.w};
            const float bvv[4] = {b.x, b.y, b.z, b.w};
            #pragma unroll
            for (int i = 0; i < 4; i++)
                #pragma unroll
                for (int j = 0; j < 4; j++)
                    acc[i][j] = fmaf(avv[i], bvv[j], acc[i][j]);
        }
        av = av2; bv = bv2;
    }

    #pragma unroll
    for (int i = 0; i < 4; i++) {
        const int col = c0 + tcol;
        float4 r;
        r.x = acc[i][0] + bx[col + 0];
        r.y = acc[i][1] + bx[col + 1];
        r.z = acc[i][2] + bx[col + 2];
        r.w = acc[i][3] + bx[col + 3];
        *(float4*)(gx + (long)(n0 + trow + i) * GXC + col) = r;
    }
}

// ---------- Kernel 2: leaves — pure elementwise -----------------------------
__global__ __launch_bounds__(256) void leaf_kernel(
    const float* __restrict__ gx, const float* __restrict__ bh,
    float* __restrict__ Hb, float* __restrict__ Cb)
{
    const int node = LEAF_FIRST + blockIdx.x;
    const int t = threadIdx.x;
    const float* g = gx + (long)node * GXC;
    const float gi = g[t]       + bh[t];
    const float go = g[512 + t] + bh[512 + t];
    const float gu = g[768 + t] + bh[768 + t];
    const float c  = sigf(gi) * tanhf(gu);
    const float h  = sigf(go) * tanhf(c);
    Hb[(long)node * HDIM + t] = h;
    Cb[(long)node * HDIM + t] = c;
}

// ---------- Kernel 3: big-level GEMM (7 sections, 64x64 tiles, dbuf) --------
// sec: 0=i, 1=o, 2=u (X = hs), 3..6 = f on child k (X = masked child h).
__global__ __launch_bounds__(256) void level_gemm(
    int first, int M, const float* __restrict__ Hb,
    const int* __restrict__ child_idx, const float* __restrict__ child_mask,
    const float* __restrict__ Wh, float* __restrict__ D)
{
    __shared__ __align__(16) float Xs[16][68];
    __shared__ __align__(16) float Ws[16][68];
    const int tid  = threadIdx.x;
    const int sec  = blockIdx.y;
    const int c0   = blockIdx.x * 64;
    const int r0   = blockIdx.z * 64;
    const int sr   = tid >> 2;
    const int sk   = (tid & 3) << 2;
    const int trow = (tid >> 4) << 2;
    const int tcol = (tid & 15) << 2;

    const float* Wg;
    if      (sec == 0) Wg = Wh;                  // i
    else if (sec == 1) Wg = Wh + 2 * WH_STRIDE;  // o
    else if (sec == 2) Wg = Wh + 3 * WH_STRIDE;  // u
    else               Wg = Wh + 1 * WH_STRIDE;  // f

    const int  nl    = c0 + sr;
    const bool valid = nl < M;
    int   ci[4];
    float cm[4] = {0.f, 0.f, 0.f, 0.f};
    if (valid) {
        const int n = first + nl;
        if (sec < 3) {
            #pragma unroll
            for (int k = 0; k < 4; k++) {
                ci[k] = child_idx[n * 4 + k];
                cm[k] = child_mask[n * 4 + k];
            }
        } else {
            ci[0] = child_idx[n * 4 + (sec - 3)];
            cm[0] = child_mask[n * 4 + (sec - 3)];
        }
    }
    const long wrow = (long)(r0 + sr) * HDIM;

    float acc[4][4] = {};

    // stage chunk k0=0
    float4 xv = make_float4(0.f, 0.f, 0.f, 0.f);
    if (valid) {
        if (sec < 3) {
            #pragma unroll
            for (int k = 0; k < 4; k++)
                if (cm[k] != 0.f) {
                    const float4 hv = *(const float4*)(Hb + (long)ci[k] * HDIM + sk);
                    xv.x += hv.x; xv.y += hv.y; xv.z += hv.z; xv.w += hv.w;
                }
        } else if (cm[0] != 0.f) {
            xv = *(const float4*)(Hb + (long)ci[0] * HDIM + sk);
        }
    }
    float4 wv = *(const float4*)(Wg + wrow + sk);

    for (int k0 = 0; k0 < HDIM; k0 += 16) {
        __syncthreads();
        Xs[sk+0][sr] = xv.x; Xs[sk+1][sr] = xv.y; Xs[sk+2][sr] = xv.z; Xs[sk+3][sr] = xv.w;
        Ws[sk+0][sr] = wv.x; Ws[sk+1][sr] = wv.y; Ws[sk+2][sr] = wv.z; Ws[sk+3][sr] = wv.w;
        __syncthreads();
        // prefetch next chunk before FMAs
        const int kn = k0 + 16;
        float4 xv2 = make_float4(0.f, 0.f, 0.f, 0.f), wv2 = xv2;
        if (kn < HDIM) {
            if (valid) {
                if (sec < 3) {
                    #pragma unroll
                    for (int k = 0; k < 4; k++)
                        if (cm[k] != 0.f) {
                            const float4 hv = *(const float4*)(Hb + (long)ci[k] * HDIM + kn + sk);
                            xv2.x += hv.x; xv2.y += hv.y; xv2.z += hv.z; xv2.w += hv.w;
                        }
                } else if (cm[0] != 0.f) {
                    xv2 = *(const float4*)(Hb + (long)ci[0] * HDIM + kn + sk);
                }
            }
            wv2 = *(const float4*)(Wg + wrow + kn + sk);
        }
        #pragma unroll
        for (int k = 0; k < 16; k++) {
            const float4 a = *(const float4*)&Ws[k][trow];
            const float4 b = *(const float4*)&Xs[k][tcol];
            const float avv[4] = {a.x, a.y, a.z, a.w};
            const float bvv[4] = {b.x, b.y, b.z, b.w};
            #pragma unroll
            for (int i = 0; i < 4; i++)
                #pragma unroll
                for (int j = 0; j < 4; j++)
                    acc[i][j] = fmaf(avv[i], bvv[j], acc[i][j]);
        }
        xv = xv2; wv = wv2;
    }

    #pragma unroll
    for (int j = 0; j < 4; j++) {
        const int col = c0 + tcol + j;
        if (col < M) {
            float4 r;
            r.x = acc[0][j]; r.y = acc[1][j]; r.z = acc[2][j]; r.w = acc[3][j];
            *(float4*)(D + ((long)(sec * M + col)) * HDIM + r0 + trow) = r;
        }
    }
}

// ---------- Kernel 4: big-level pointwise combine ---------------------------
__global__ __launch_bounds__(256) void level_pointwise(
    int first, int M, const float* __restrict__ gx, const float* __restrict__ D,
    const int* __restrict__ child_idx, const float* __restrict__ child_mask,
    const float* __restrict__ bh, float* __restrict__ Hb, float* __restrict__ Cb)
{
    const int nl = blockIdx.x;
    const int n  = first + nl;
    const int t  = threadIdx.x;
    const float di = D[((long)(0 * M + nl)) * HDIM + t];
    const float dO = D[((long)(1 * M + nl)) * HDIM + t];
    const float du = D[((long)(2 * M + nl)) * HDIM + t];
    const float* g = gx + (long)n * GXC;
    const float gi  = g[t]       + bh[t]       + di;
    const float gfb = g[256 + t] + bh[256 + t];
    const float go  = g[512 + t] + bh[512 + t] + dO;
    const float gu  = g[768 + t] + bh[768 + t] + du;

    float c = sigf(gi) * tanhf(gu);
    #pragma unroll
    for (int k = 0; k < 4; k++) {
        const float m = child_mask[n * 4 + k];
        if (m != 0.f) {
            const int ci = child_idx[n * 4 + k];
            const float df = D[((long)((3 + k) * M + nl)) * HDIM + t];
            const float cc = Cb[(long)ci * HDIM + t];
            c = fmaf(sigf(gfb + df), cc, c);
        }
    }
    const float h = sigf(go) * tanhf(c);
    Hb[(long)n * HDIM + t] = h;
    Cb[(long)n * HDIM + t] = c;
}

// ---------- Kernel 5: fused small-level kernel — one block per node ---------
// 7 GEMVs (i,o,u on hs; f on each child h) via row-per-wave shuffle reduce,
// then the pointwise. doOut: also compute root logits + log_softmax.
__global__ __launch_bounds__(256) void level_fused(
    int first, const float* __restrict__ gx, const int* __restrict__ child_idx,
    const float* __restrict__ child_mask, const float* __restrict__ Wh,
    const float* __restrict__ bh, float* __restrict__ Hb, float* __restrict__ Cb,
    int doOut, const float* __restrict__ Wout, const float* __restrict__ bout,
    float* __restrict__ out)
{
    const int n    = first + blockIdx.x;
    const int tid  = threadIdx.x;
    const int wave = tid >> 6;
    const int lane = tid & 63;

    __shared__ __align__(16) float hsX[5][HDIM];   // [0]=hs, [1..4]=child h
    __shared__ float dots[7][HDIM];

    int   ci[4];
    float cm[4], cc[4];
    #pragma unroll
    for (int k = 0; k < 4; k++) {
        ci[k] = child_idx[n * 4 + k];
        cm[k] = child_mask[n * 4 + k];
    }
    float hsum = 0.f;
    #pragma unroll
    for (int k = 0; k < 4; k++) {
        float hv = 0.f, cv = 0.f;
        if (cm[k] != 0.f) {
            hv = Hb[(long)ci[k] * HDIM + tid];
            cv = Cb[(long)ci[k] * HDIM + tid];
        }
        hsX[1 + k][tid] = hv;
        cc[k] = cv;
        hsum += hv;
    }
    hsX[0][tid] = hsum;
    __syncthreads();

    // 7 GEMVs. m: 0->Wi·hs, 1->Wo·hs, 2->Wu·hs, 3..6->Wf·hc[m-3].
    #pragma unroll
    for (int m = 0; m < 7; m++) {
        const float* Wg;
        int xi;
        if      (m == 0) { Wg = Wh;                  xi = 0; }
        else if (m == 1) { Wg = Wh + 2 * WH_STRIDE;  xi = 0; }
        else if (m == 2) { Wg = Wh + 3 * WH_STRIDE;  xi = 0; }
        else             { Wg = Wh + 1 * WH_STRIDE;  xi = m - 2; }
        const float4 xq = *(const float4*)&hsX[xi][lane << 2];
        const float* Wrow = Wg + (long)(wave * 64) * HDIM + (lane << 2);
        #pragma unroll 4
        for (int j = 0; j < 64; j++) {
            const float4 wv = *(const float4*)(Wrow + (long)j * HDIM);
            float s = dot4(0.f, wv, xq);
            s += __shfl_down(s, 32, 64);
            s += __shfl_down(s, 16, 64);
            s += __shfl_down(s,  8, 64);
            s += __shfl_down(s,  4, 64);
            s += __shfl_down(s,  2, 64);
            s += __shfl_down(s,  1, 64);
            if (lane == 0) dots[m][wave * 64 + j] = s;
        }
    }
    __syncthreads();

    // Pointwise
    const float* g = gx + (long)n * GXC;
    const float gi  = g[tid]       + bh[tid]       + dots[0][tid];
    const float gfb = g[256 + tid] + bh[256 + tid];
    const float go  = g[512 + tid] + bh[512 + tid] + dots[1][tid];
    const float gu  = g[768 + tid] + bh[768 + tid] + dots[2][tid];

    float c = sigf(gi) * tanhf(gu);
    #pragma unroll
    for (int k = 0; k < 4; k++)
        if (cm[k] != 0.f)
            c = fmaf(sigf(gfb + dots[3 + k][tid]), cc[k], c);
    const float h = sigf(go) * tanhf(c);
    Hb[(long)n * HDIM + tid] = h;
    Cb[(long)n * HDIM + tid] = c;

    if (doOut) {
        __syncthreads();
        hsX[0][tid] = h;          // root h
        __syncthreads();
        const int o = tid >> 6;
        float s = 0.f;
        for (int j = lane; j < HDIM; j += 64)
            s = fmaf(Wout[o * HDIM + j], hsX[0][j], s);
        #pragma unroll
        for (int off = 32; off > 0; off >>= 1)
            s += __shfl_down(s, off, 64);
        __shared__ float logits[4];
        if (lane == 0) logits[o] = s + bout[o];
        __syncthreads();
        if (tid == 0) {
            float mx = logits[0];
            #pragma unroll
            for (int i = 1; i < 4; i++) mx = fmaxf(mx, logits[i]);
            float se = 0.f;
            #pragma unroll
            for (int i = 0; i < 4; i++) se += __expf(logits[i] - mx);
            const float lse = mx + __logf(se);
            #pragma unroll
            for (int i = 0; i < 4; i++) out[i] = logits[i] - lse;
        }
    }
}

extern "C" void kernel_launch(void* const* d_in, const int* in_sizes, int n_in,
                              void* d_out, int out_size, void* d_ws, size_t ws_size,
                              hipStream_t stream)
{
    const int*   xs         = (const int*)  d_in[0];
    const int*   child_idx  = (const int*)  d_in[1];
    const float* child_mask = (const float*)d_in[2];
    const float* emb        = (const float*)d_in[3];
    const float* Wx         = (const float*)d_in[4];
    const float* bx         = (const float*)d_in[5];
    const float* Wh         = (const float*)d_in[6];
    const float* bh         = (const float*)d_in[7];
    const float* Wout       = (const float*)d_in[8];
    const float* bout       = (const float*)d_in[9];
    float* out = (float*)d_out;

    float* gxb  = (float*)d_ws;                       // [8192][1024]
    float* Hb   = gxb + (size_t)N_NODES * GXC;        // [8192][256]
    float* Cb   = Hb  + (size_t)N_NODES * HDIM;       // [8192][256]
    float* Dbuf = gxb + (size_t)LEAF_FIRST * GXC;     // aliases leaf gx rows

    gx_gemm<<<dim3(GXC / 64, N_NODES / 64), 256, 0, stream>>>(xs, emb, Wx, bx, gxb);
    leaf_kernel<<<N_NODES - LEAF_FIRST, 256, 0, stream>>>(gxb, bh, Hb, Cb);

    const int pf[7] = {1365, 341, 85, 21, 5, 1, 0};
    const int pc[7] = { 683, 1024, 256, 64, 16, 4, 1};

    // Big levels: tiled GEMM + pointwise (2 launches each)
    for (int p = 0; p < 2; p++) {
        const int M = pc[p];
        level_gemm<<<dim3((M + 63) / 64, 7, 4), 256, 0, stream>>>(
            pf[p], M, Hb, child_idx, child_mask, Wh, Dbuf);
        level_pointwise<<<M, 256, 0, stream>>>(
            pf[p], M, gxb, Dbuf, child_idx, child_mask, bh, Hb, Cb);
    }
    // Small levels: fused one-block-per-node (1 launch each); root fuses output.
    for (int p = 2; p < 7; p++) {
        level_fused<<<pc[p], 256, 0, stream>>>(
            pf[p], gxb, child_idx, child_mask, Wh, bh, Hb, Cb,
            (p == 6) ? 1 : 0, Wout, bout, out);
    }
}

// Round 8
// 626.645 us; speedup vs baseline: 2.0250x; 1.5698x over previous
//
#include <hip/hip_runtime.h>

// ChildSumTreeLSTM on a static 4-ary heap tree.
// N=8192, H=256, D=300, K=4, OUT=4. Leaves = 2048..8191. Internal 0..2047, 7 levels.
// Measured facts driving this structure:
//  - launch boundary ~12-20 us; in-kernel grid sync ~60-70 us (rounds 4/6): use
//    few plain launches, never cooperative.
//  - shuffle-reduce GEMV is latency-poisoned (round 7): use row-per-thread
//    serial-K GEMV against TRANSPOSED Wh (coalesced), fused with pointwise.
// Launches: gx_gemm(+WT transpose blocks) -> leaf -> 7x level_fused2 = 9 total.
// Workspace (50.3 MB, unchanged):
//   gx : [8192][1024] f32   (gate order i,f,o,u)
//   Hb : [8192][256]  f32
//   Cb : [8192][256]  f32
// WT[g][k][r] (1 MB) lives in the DEAD f-gate slots of leaf gx rows 2048..3071:
//   WT(g,k,r) = gx[(2048 + g*256 + k)*1024 + 256 + r]
// (gx_gemm skips computing leaf f-columns; leaf_kernel never reads them.)

#define N_NODES 8192
#define HDIM 256
#define DDIM 300
#define GXC 1024
#define LEAF_FIRST 2048
#define WH_STRIDE 65536   // 256*256
#define NPB 4             // nodes per block in level_fused2

__device__ __forceinline__ float sigf(float x) { return 1.0f / (1.0f + __expf(-x)); }

// ---------- Kernel 1: gx GEMM + WT transpose (extra grid.y row) -------------
// y < 128 : gx[n][c] = emb[xs[n]] . Wx[c] + bx[c], 64x64 tile.
//           Leaf rows (n>=2048) skip dead f-cols [256,512).
// y == 128: 16 blocks transpose Wh into the WT slots (reads Wh only, writes
//           dead leaf-f slots -> no race with the GEMM blocks).
__global__ __launch_bounds__(256) void gx_gemm(
    const int* __restrict__ xs, const float* __restrict__ emb,
    const float* __restrict__ Wx, const float* __restrict__ bx,
    const float* __restrict__ Wh, float* __restrict__ gx)
{
    const int tid = threadIdx.x;

    if (blockIdx.y == 128) {                 // ---- WT transpose blocks ----
        const int b  = blockIdx.x;           // 0..15
        const int g  = b >> 2;               // gate 0..3 (i,f,o,u)
        const int k0 = (b & 3) << 6;         // k-range start (64 k's)
        // WT(g,k,r) = Wh[g][r][k]; write coalesced in r=tid.
        for (int kk = 0; kk < 64; kk++) {
            const int k = k0 + kk;
            const float w = Wh[(long)g * WH_STRIDE + (long)tid * HDIM + k];
            gx[(long)(LEAF_FIRST + g * 256 + k) * GXC + 256 + tid] = w;
        }
        return;
    }

    const int n0 = blockIdx.y * 64;
    const int c0 = blockIdx.x * 64;
    if (n0 >= LEAF_FIRST && c0 >= 256 && c0 < 512) return;  // dead leaf f-cols

    __shared__ __align__(16) float As[16][68];
    __shared__ __align__(16) float Bs[16][68];
    const int sr   = tid >> 2;
    const int sk   = (tid & 3) << 2;
    const int trow = (tid >> 4) << 2;
    const int tcol = (tid & 15) << 2;

    const long arow = (long)xs[n0 + sr] * DDIM;
    const long brow = (long)(c0 + sr) * DDIM;

    float acc[4][4] = {};

    for (int k0 = 0; k0 < DDIM; k0 += 16) {
        float4 av = make_float4(0.f, 0.f, 0.f, 0.f), bv = av;
        if (k0 + sk < DDIM) {
            av = *(const float4*)(emb + arow + k0 + sk);
            bv = *(const float4*)(Wx  + brow + k0 + sk);
        }
        __syncthreads();
        As[sk+0][sr] = av.x; As[sk+1][sr] = av.y; As[sk+2][sr] = av.z; As[sk+3][sr] = av.w;
        Bs[sk+0][sr] = bv.x; Bs[sk+1][sr] = bv.y; Bs[sk+2][sr] = bv.z; Bs[sk+3][sr] = bv.w;
        __syncthreads();
        #pragma unroll
        for (int k = 0; k < 16; k++) {
            const float4 a = *(const float4*)&As[k][trow];
            const float4 b = *(const float4*)&Bs[k][tcol];
            const float avv[4] = {a.x, a.y, a.z, a.w};
            const float bvv[4] = {b.x, b.y, b.z, b.w};
            #pragma unroll
            for (int i = 0; i < 4; i++)
                #pragma unroll
                for (int j = 0; j < 4; j++)
                    acc[i][j] = fmaf(avv[i], bvv[j], acc[i][j]);
        }
    }

    #pragma unroll
    for (int i = 0; i < 4; i++) {
        const int col = c0 + tcol;
        float4 r;
        r.x = acc[i][0] + bx[col + 0];
        r.y = acc[i][1] + bx[col + 1];
        r.z = acc[i][2] + bx[col + 2];
        r.w = acc[i][3] + bx[col + 3];
        *(float4*)(gx + (long)(n0 + trow + i) * GXC + col) = r;
    }
}

// ---------- Kernel 2: leaves — pure elementwise -----------------------------
__global__ __launch_bounds__(256) void leaf_kernel(
    const float* __restrict__ gx, const float* __restrict__ bh,
    float* __restrict__ Hb, float* __restrict__ Cb)
{
    const int node = LEAF_FIRST + blockIdx.x;
    const int t = threadIdx.x;
    const float* g = gx + (long)node * GXC;
    const float gi = g[t]       + bh[t];
    const float go = g[512 + t] + bh[512 + t];
    const float gu = g[768 + t] + bh[768 + t];
    const float c  = sigf(gi) * tanhf(gu);
    const float h  = sigf(go) * tanhf(c);
    Hb[(long)node * HDIM + t] = h;
    Cb[(long)node * HDIM + t] = c;
}

// ---------- Kernel 3: fused level — GEMV(transposed W) + pointwise ----------
// NPB nodes per block. Thread t owns output row t: serial k-loop, coalesced
// WT loads (stride-1024 between k), float4 LDS broadcasts for X. No shuffles.
__global__ __launch_bounds__(256) void level_fused2(
    int first, int M, const float* __restrict__ gx,
    const float* __restrict__ WT,          // = gx + 2048*1024 + 256; (g*256+k)*1024 + r
    const int* __restrict__ child_idx, const float* __restrict__ child_mask,
    const float* __restrict__ bh, float* __restrict__ Hb, float* __restrict__ Cb,
    int doOut, const float* __restrict__ Wout, const float* __restrict__ bout,
    float* __restrict__ out)
{
    const int tid   = threadIdx.x;
    const int nbase = first + blockIdx.x * NPB;
    const int nend  = first + M;

    __shared__ __align__(16) float Xs[NPB][5][HDIM];   // [j][0]=hs, [j][1..4]=child h

    int   ci[NPB][4];
    float cm[NPB][4];
    #pragma unroll
    for (int j = 0; j < NPB; j++) {
        const int  n = nbase + j;
        const bool v = n < nend;
        float hsum = 0.f;
        #pragma unroll
        for (int k = 0; k < 4; k++) {
            int c = 0; float m = 0.f;
            if (v) { c = child_idx[n * 4 + k]; m = child_mask[n * 4 + k]; }
            ci[j][k] = c; cm[j][k] = m;
            const float hv = (m != 0.f) ? Hb[(long)c * HDIM + tid] : 0.f;
            Xs[j][1 + k][tid] = hv;
            hsum += hv;
        }
        Xs[j][0][tid] = hsum;
    }
    __syncthreads();

    float ai[NPB] = {}, ao[NPB] = {}, au[NPB] = {}, af[NPB][4] = {};
    const float* WTi = WT + (long)(0 * 256) * GXC;
    const float* WTf = WT + (long)(1 * 256) * GXC;
    const float* WTo = WT + (long)(2 * 256) * GXC;
    const float* WTu = WT + (long)(3 * 256) * GXC;

    for (int k0 = 0; k0 < HDIM; k0 += 4) {
        float wi[4], wf[4], wo[4], wu[4];
        #pragma unroll
        for (int kk = 0; kk < 4; kk++) {
            const long off = (long)(k0 + kk) * GXC + tid;
            wi[kk] = WTi[off]; wf[kk] = WTf[off];
            wo[kk] = WTo[off]; wu[kk] = WTu[off];
        }
        #pragma unroll
        for (int j = 0; j < NPB; j++) {
            const float4 xs = *(const float4*)&Xs[j][0][k0];
            const float4 x0 = *(const float4*)&Xs[j][1][k0];
            const float4 x1 = *(const float4*)&Xs[j][2][k0];
            const float4 x2 = *(const float4*)&Xs[j][3][k0];
            const float4 x3 = *(const float4*)&Xs[j][4][k0];
            ai[j] = fmaf(wi[0], xs.x, ai[j]); ai[j] = fmaf(wi[1], xs.y, ai[j]);
            ai[j] = fmaf(wi[2], xs.z, ai[j]); ai[j] = fmaf(wi[3], xs.w, ai[j]);
            ao[j] = fmaf(wo[0], xs.x, ao[j]); ao[j] = fmaf(wo[1], xs.y, ao[j]);
            ao[j] = fmaf(wo[2], xs.z, ao[j]); ao[j] = fmaf(wo[3], xs.w, ao[j]);
            au[j] = fmaf(wu[0], xs.x, au[j]); au[j] = fmaf(wu[1], xs.y, au[j]);
            au[j] = fmaf(wu[2], xs.z, au[j]); au[j] = fmaf(wu[3], xs.w, au[j]);
            af[j][0] = fmaf(wf[0], x0.x, af[j][0]); af[j][0] = fmaf(wf[1], x0.y, af[j][0]);
            af[j][0] = fmaf(wf[2], x0.z, af[j][0]); af[j][0] = fmaf(wf[3], x0.w, af[j][0]);
            af[j][1] = fmaf(wf[0], x1.x, af[j][1]); af[j][1] = fmaf(wf[1], x1.y, af[j][1]);
            af[j][1] = fmaf(wf[2], x1.z, af[j][1]); af[j][1] = fmaf(wf[3], x1.w, af[j][1]);
            af[j][2] = fmaf(wf[0], x2.x, af[j][2]); af[j][2] = fmaf(wf[1], x2.y, af[j][2]);
            af[j][2] = fmaf(wf[2], x2.z, af[j][2]); af[j][2] = fmaf(wf[3], x2.w, af[j][2]);
            af[j][3] = fmaf(wf[0], x3.x, af[j][3]); af[j][3] = fmaf(wf[1], x3.y, af[j][3]);
            af[j][3] = fmaf(wf[2], x3.z, af[j][3]); af[j][3] = fmaf(wf[3], x3.w, af[j][3]);
        }
    }

    // Pointwise (thread t owns h-index t for each of its NPB nodes)
    #pragma unroll
    for (int j = 0; j < NPB; j++) {
        const int n = nbase + j;
        if (n >= nend) break;                       // uniform across block
        const float* g = gx + (long)n * GXC;
        const float gi  = g[tid]       + bh[tid]       + ai[j];
        const float gfb = g[256 + tid] + bh[256 + tid];
        const float go  = g[512 + tid] + bh[512 + tid] + ao[j];
        const float gu  = g[768 + tid] + bh[768 + tid] + au[j];
        float c = sigf(gi) * tanhf(gu);
        #pragma unroll
        for (int k = 0; k < 4; k++)
            if (cm[j][k] != 0.f)
                c = fmaf(sigf(gfb + af[j][k]),
                         Cb[(long)ci[j][k] * HDIM + tid], c);
        const float h = sigf(go) * tanhf(c);
        Hb[(long)n * HDIM + tid] = h;
        Cb[(long)n * HDIM + tid] = c;

        if (doOut && n == 0) {                      // root: fused output
            __syncthreads();
            Xs[0][0][tid] = h;
            __syncthreads();
            const int o    = tid >> 6;
            const int lane = tid & 63;
            float s = 0.f;
            for (int q = lane; q < HDIM; q += 64)
                s = fmaf(Wout[o * HDIM + q], Xs[0][0][q], s);
            #pragma unroll
            for (int off = 32; off > 0; off >>= 1)
                s += __shfl_down(s, off, 64);
            __shared__ float logits[4];
            if (lane == 0) logits[o] = s + bout[o];
            __syncthreads();
            if (tid == 0) {
                float mx = logits[0];
                #pragma unroll
                for (int i = 1; i < 4; i++) mx = fmaxf(mx, logits[i]);
                float se = 0.f;
                #pragma unroll
                for (int i = 0; i < 4; i++) se += __expf(logits[i] - mx);
                const float lse = mx + __logf(se);
                #pragma unroll
                for (int i = 0; i < 4; i++) out[i] = logits[i] - lse;
            }
        }
    }
}

extern "C" void kernel_launch(void* const* d_in, const int* in_sizes, int n_in,
                              void* d_out, int out_size, void* d_ws, size_t ws_size,
                              hipStream_t stream)
{
    const int*   xs         = (const int*)  d_in[0];
    const int*   child_idx  = (const int*)  d_in[1];
    const float* child_mask = (const float*)d_in[2];
    const float* emb        = (const float*)d_in[3];
    const float* Wx         = (const float*)d_in[4];
    const float* bx         = (const float*)d_in[5];
    const float* Wh         = (const float*)d_in[6];
    const float* bh         = (const float*)d_in[7];
    const float* Wout       = (const float*)d_in[8];
    const float* bout       = (const float*)d_in[9];
    float* out = (float*)d_out;

    float* gxb = (float*)d_ws;                        // [8192][1024]
    float* Hb  = gxb + (size_t)N_NODES * GXC;         // [8192][256]
    float* Cb  = Hb  + (size_t)N_NODES * HDIM;        // [8192][256]
    const float* WT = gxb + (size_t)LEAF_FIRST * GXC + 256;  // dead leaf f-slots

    // grid.y: 128 GEMM row-tiles + 1 WT-transpose row (16 blocks used)
    gx_gemm<<<dim3(GXC / 64, 129), 256, 0, stream>>>(xs, emb, Wx, bx, Wh, gxb);
    leaf_kernel<<<N_NODES - LEAF_FIRST, 256, 0, stream>>>(gxb, bh, Hb, Cb);

    const int pf[7] = {1365, 341, 85, 21, 5, 1, 0};
    const int pc[7] = { 683, 1024, 256, 64, 16, 4, 1};
    for (int p = 0; p < 7; p++) {
        const int nblk = (pc[p] + NPB - 1) / NPB;
        level_fused2<<<nblk, 256, 0, stream>>>(
            pf[p], pc[p], gxb, WT, child_idx, child_mask, bh, Hb, Cb,
            (p == 6) ? 1 : 0, Wout, bout, out);
    }
}